// Round 20
// baseline (1583.835 us; speedup 1.0000x reference)
//
#include <hip/hip_runtime.h>
#include <hip/hip_bf16.h>
#include <math.h>
#include <stdint.h>

#define N_N 20000
#define E_E 320000
#define B_B 256
#define D_D 64
#define H_H 4
#define HC  256
#define SCALE_ 0.125f   // 1/sqrt(64)

__device__ __forceinline__ float sigmoidf_(float x) { return 1.0f / (1.0f + expf(-x)); }

__device__ __forceinline__ void atomicMaxF(float* addr, float val) {
    if (val >= 0.0f) atomicMax((int*)addr, __float_as_int(val));
    else             atomicMin((unsigned int*)addr, __float_as_uint(val));
}

// ---------------- Threefry2x32 (KAT-verified r5) ----------------------------
__device__ __forceinline__ void tf_round(uint32_t& x0, uint32_t& x1, int R) {
    x0 += x1; x1 = (x1 << R) | (x1 >> (32 - R)); x1 ^= x0;
}
__device__ void threefry2x32(uint32_t k0, uint32_t k1, uint32_t c0, uint32_t c1,
                             uint32_t& o0, uint32_t& o1) {
    const int rot[8] = {13, 15, 26, 6, 17, 29, 16, 24};
    uint32_t ks[3] = {k0, k1, k0 ^ k1 ^ 0x1BD11BDAu};
    uint32_t x0 = c0 + ks[0], x1 = c1 + ks[1];
#pragma unroll
    for (int g = 0; g < 5; ++g) {
        const int base = (g & 1) ? 4 : 0;
        tf_round(x0, x1, rot[base + 0]); tf_round(x0, x1, rot[base + 1]);
        tf_round(x0, x1, rot[base + 2]); tf_round(x0, x1, rot[base + 3]);
        x0 += ks[(g + 1) % 3]; x1 += ks[(g + 2) % 3] + (uint32_t)(g + 1);
    }
    o0 = x0; o1 = x1;
}

// jax f32 bits->normal: f=(bits>>9|1.0f)-1; u=2f+lo; sqrt2*erfinv(u)
__device__ __forceinline__ float jax_n32(uint32_t bits) {
    float f = __uint_as_float((bits >> 9) | 0x3f800000u) - 1.0f;
    const float lo = -0x1.fffffep-1f;
    float u = 2.0f * f + lo;
    u = fmaxf(lo, u);
    return 1.41421356237f * erfinvf(u);
}

// ---------------- eps: jax partitionable 32-bit = XOR FOLD of output pair ---
// counts = iota(u64); x_hi = counts>>32 = 0, x_lo = counts = i;
// bits1, bits2 = threefry2x32(key=(0,42), x_hi, x_lo); bits = bits1 ^ bits2.
__global__ void k_eps(float* __restrict__ eps) {
    int i = blockIdx.x * 256 + threadIdx.x;
    if (i >= 32768) return;
    uint32_t o0, o1;
    threefry2x32(0u, 42u, 0u, (uint32_t)i, o0, o1);
    eps[i] = jax_n32(o0 ^ o1);
}

// ---------------- per-layer init --------------------------------------------
__global__ void k_init_layer(float* __restrict__ outm, float* __restrict__ mN,
                             float* __restrict__ den, float* __restrict__ bnst) {
    int t = blockIdx.x * 256 + threadIdx.x;
    if (t < N_N * D_D) outm[t] = 0.0f;
    if (t < N_N * H_H) { mN[t] = -INFINITY; den[t] = 0.0f; }
    if (t < 128) bnst[t] = 0.0f;
}

// ---------------- fused projection ------------------------------------------
__global__ void k_proj(const float* __restrict__ hin,
                       const float* __restrict__ Wq, const float* __restrict__ bq,
                       const float* __restrict__ Wk, const float* __restrict__ bk,
                       const float* __restrict__ Wv, const float* __restrict__ bv,
                       const float* __restrict__ Ws, const float* __restrict__ bs,
                       float* __restrict__ q, float* __restrict__ k,
                       float* __restrict__ v, float* __restrict__ xr) {
    __shared__ float hs[8][64];
    const int i0 = blockIdx.x * 8;
    const int tid = threadIdx.x;
    for (int t = tid; t < 8 * 64; t += 256) hs[t >> 6][t & 63] = hin[i0 * 64 + t];
    __syncthreads();
    const int c = tid;
    float acc[8];
    {
        float b = bq[c];
#pragma unroll
        for (int r = 0; r < 8; r++) acc[r] = b;
        for (int d = 0; d < 64; d++) {
            float w = Wq[d * 256 + c];
#pragma unroll
            for (int r = 0; r < 8; r++) acc[r] += hs[r][d] * w;
        }
#pragma unroll
        for (int r = 0; r < 8; r++) q[(i0 + r) * 256 + c] = acc[r];
    }
    {
        float b = bk[c];
#pragma unroll
        for (int r = 0; r < 8; r++) acc[r] = b;
        for (int d = 0; d < 64; d++) {
            float w = Wk[d * 256 + c];
#pragma unroll
            for (int r = 0; r < 8; r++) acc[r] += hs[r][d] * w;
        }
#pragma unroll
        for (int r = 0; r < 8; r++) k[(i0 + r) * 256 + c] = acc[r];
    }
    {
        float b = bv[c];
#pragma unroll
        for (int r = 0; r < 8; r++) acc[r] = b;
        for (int d = 0; d < 64; d++) {
            float w = Wv[d * 256 + c];
#pragma unroll
            for (int r = 0; r < 8; r++) acc[r] += hs[r][d] * w;
        }
#pragma unroll
        for (int r = 0; r < 8; r++) v[(i0 + r) * 256 + c] = acc[r];
    }
    if (c < 64) {
        float b = bs[c];
#pragma unroll
        for (int r = 0; r < 8; r++) acc[r] = b;
        for (int d = 0; d < 64; d++) {
            float w = Ws[d * 64 + c];
#pragma unroll
            for (int r = 0; r < 8; r++) acc[r] += hs[r][d] * w;
        }
#pragma unroll
        for (int r = 0; r < 8; r++) xr[(i0 + r) * 64 + c] = acc[r];
    }
}

// ---------------- edge pass 1 -----------------------------------------------
__global__ void k_edge_alpha(const float* __restrict__ q, const float* __restrict__ kk,
                             const float* __restrict__ eattr, const float* __restrict__ We,
                             const int* __restrict__ ei,
                             float* __restrict__ alpha, float* __restrict__ mN) {
    int e = blockIdx.x * 4 + (threadIdx.x >> 6);
    if (e >= E_E) return;
    int lane = threadIdx.x & 63;
    int src = ei[e], dst = ei[E_E + e];
    float a0 = eattr[e * 4 + 0], a1 = eattr[e * 4 + 1];
    float a2 = eattr[e * 4 + 2], a3 = eattr[e * 4 + 3];
    float part[4];
#pragma unroll
    for (int h = 0; h < 4; h++) {
        int c = h * 64 + lane;
        float ev = a0 * We[c] + a1 * We[256 + c] + a2 * We[512 + c] + a3 * We[768 + c];
        part[h] = q[dst * 256 + c] * (kk[src * 256 + c] + ev);
    }
#pragma unroll
    for (int off = 32; off > 0; off >>= 1) {
#pragma unroll
        for (int h = 0; h < 4; h++) part[h] += __shfl_down(part[h], off);
    }
    if (lane == 0) {
#pragma unroll
        for (int h = 0; h < 4; h++) {
            float al = part[h] * SCALE_;
            alpha[e * 4 + h] = al;
            atomicMaxF(&mN[dst * 4 + h], al);
        }
    }
}

// ---------------- edge pass 2 -----------------------------------------------
__global__ void k_edge_exp(const int* __restrict__ ei, float* __restrict__ alpha,
                           const float* __restrict__ mN, float* __restrict__ den) {
    int t = blockIdx.x * 256 + threadIdx.x;
    if (t >= E_E * H_H) return;
    int e = t >> 2, h = t & 3;
    int dst = ei[E_E + e];
    float ex = expf(alpha[t] - mN[dst * 4 + h]);
    alpha[t] = ex;
    atomicAdd(&den[dst * 4 + h], ex);
}

// ---------------- edge pass 3 -----------------------------------------------
__global__ void k_edge_msg(const float* __restrict__ v, const float* __restrict__ eattr,
                           const float* __restrict__ We, const int* __restrict__ ei,
                           const float* __restrict__ exA, const float* __restrict__ den,
                           float* __restrict__ outm) {
    int e = blockIdx.x * 4 + (threadIdx.x >> 6);
    if (e >= E_E) return;
    int lane = threadIdx.x & 63;
    int src = ei[e], dst = ei[E_E + e];
    float a0 = eattr[e * 4 + 0], a1 = eattr[e * 4 + 1];
    float a2 = eattr[e * 4 + 2], a3 = eattr[e * 4 + 3];
    float acc = 0.0f;
#pragma unroll
    for (int h = 0; h < 4; h++) {
        int c = h * 64 + lane;
        float ev = a0 * We[c] + a1 * We[256 + c] + a2 * We[512 + c] + a3 * We[768 + c];
        float a = exA[e * 4 + h] / (den[dst * 4 + h] + 1e-16f);
        acc += a * (v[src * 256 + c] + ev);
    }
    atomicAdd(&outm[dst * 64 + lane], acc * 0.25f);
}

// ---------------- beta gate + relu ------------------------------------------
__global__ void k_finalize(const float* __restrict__ outm, const float* __restrict__ xr,
                           const float* __restrict__ Wb, float* __restrict__ h) {
    int i = blockIdx.x * 4 + (threadIdx.x >> 6);
    if (i >= N_N) return;
    int lane = threadIdx.x & 63;
    float o = outm[i * 64 + lane], x = xr[i * 64 + lane];
    float p = o * Wb[lane] + x * Wb[64 + lane] + (o - x) * Wb[128 + lane];
#pragma unroll
    for (int off = 32; off > 0; off >>= 1) p += __shfl_down(p, off);
    float s = __shfl(p, 0);
    float beta = sigmoidf_(s);
    float val = beta * x + (1.0f - beta) * o;
    h[i * 64 + lane] = fmaxf(val, 0.0f);
}

// ---------------- batchnorm -------------------------------------------------
__global__ void k_bn_stats(const float* __restrict__ h, float* __restrict__ bnst) {
    int c = threadIdx.x & 63, g = threadIdx.x >> 6;
    float s = 0.0f, s2 = 0.0f;
    for (int i = blockIdx.x * 4 + g; i < N_N; i += gridDim.x * 4) {
        float v = h[i * 64 + c];
        s += v; s2 += v * v;
    }
    atomicAdd(&bnst[c], s);
    atomicAdd(&bnst[64 + c], s2);
}

__global__ void k_bn_apply(float* __restrict__ h, const float* __restrict__ bnst,
                           const float* __restrict__ gamma, const float* __restrict__ beta) {
    int t = blockIdx.x * 256 + threadIdx.x;
    if (t >= N_N * D_D) return;
    int c = t & 63;
    float mu = bnst[c] * (1.0f / N_N);
    float var = bnst[64 + c] * (1.0f / N_N) - mu * mu;
    h[t] = gamma[c] * (h[t] - mu) * rsqrtf(var + 1e-5f) + beta[c];
}

// ---------------- set2set ---------------------------------------------------
__global__ void k_s2s_init(float* __restrict__ hl, float* __restrict__ cl,
                           float* __restrict__ qstar) {
    int t = blockIdx.x * 256 + threadIdx.x;
    if (t < B_B * D_D) { hl[t] = 0.0f; cl[t] = 0.0f; }
    if (t < B_B * 2 * D_D) qstar[t] = 0.0f;
}

__global__ void k_lstm(const float* __restrict__ qstar, float* __restrict__ hl,
                       float* __restrict__ cl,
                       const float* __restrict__ Wih, const float* __restrict__ Whh,
                       const float* __restrict__ bih, const float* __restrict__ bhh,
                       float* __restrict__ mB, float* __restrict__ denB, float* __restrict__ r) {
    int b = blockIdx.x, tid = threadIdx.x;
    __shared__ float qs[128], hs[64], gates[256];
    if (tid < 128) qs[tid] = qstar[b * 128 + tid];
    if (tid < 64) hs[tid] = hl[b * 64 + tid];
    __syncthreads();
    float acc = bih[tid] + bhh[tid];
    for (int j = 0; j < 128; j++) acc += qs[j] * Wih[tid * 128 + j];
    for (int j = 0; j < 64; j++) acc += hs[j] * Whh[tid * 64 + j];
    gates[tid] = acc;
    __syncthreads();
    if (tid < 64) {
        float ig = sigmoidf_(gates[tid]);
        float fg = sigmoidf_(gates[64 + tid]);
        float gg = tanhf(gates[128 + tid]);
        float og = sigmoidf_(gates[192 + tid]);
        float c = fg * cl[b * 64 + tid] + ig * gg;
        float hh = og * tanhf(c);
        cl[b * 64 + tid] = c;
        hl[b * 64 + tid] = hh;
        r[b * 64 + tid] = 0.0f;
    }
    if (tid == 0) { mB[b] = -INFINITY; denB[b] = 0.0f; }
}

__global__ void k_s2s_dot(const float* __restrict__ h, const float* __restrict__ hl,
                          const int* __restrict__ batch, float* __restrict__ eN,
                          float* __restrict__ mB) {
    int i = blockIdx.x * 4 + (threadIdx.x >> 6);
    if (i >= N_N) return;
    int lane = threadIdx.x & 63;
    int b = batch[i];
    float p = h[i * 64 + lane] * hl[b * 64 + lane];
#pragma unroll
    for (int off = 32; off > 0; off >>= 1) p += __shfl_down(p, off);
    if (lane == 0) { eN[i] = p; atomicMaxF(&mB[b], p); }
}

__global__ void k_s2s_exp(const int* __restrict__ batch, const float* __restrict__ eN,
                          const float* __restrict__ mB, float* __restrict__ exN,
                          float* __restrict__ denB) {
    int i = blockIdx.x * 256 + threadIdx.x;
    if (i >= N_N) return;
    int b = batch[i];
    float ex = expf(eN[i] - mB[b]);
    exN[i] = ex;
    atomicAdd(&denB[b], ex);
}

__global__ void k_s2s_r(const float* __restrict__ h, const int* __restrict__ batch,
                        const float* __restrict__ exN, const float* __restrict__ denB,
                        float* __restrict__ r) {
    int i = blockIdx.x * 4 + (threadIdx.x >> 6);
    if (i >= N_N) return;
    int lane = threadIdx.x & 63;
    int b = batch[i];
    float a = exN[i] / (denB[b] + 1e-16f);
    atomicAdd(&r[b * 64 + lane], a * h[i * 64 + lane]);
}

__global__ void k_s2s_q(const float* __restrict__ hl, const float* __restrict__ r,
                        float* __restrict__ qstar) {
    int t = blockIdx.x * 256 + threadIdx.x;
    if (t >= B_B * 2 * D_D) return;
    int b = t >> 7, c = t & 127;
    qstar[t] = (c < 64) ? hl[b * 64 + c] : r[b * 64 + (c - 64)];
}

// ---------------- heads + reparameterization --------------------------------
__global__ void k_final(const float* __restrict__ qstar,
                        const float* __restrict__ Wmu, const float* __restrict__ bmu,
                        const float* __restrict__ Wlv, const float* __restrict__ blv,
                        const float* __restrict__ epsb,
                        float* __restrict__ outp) {
    int b = blockIdx.x, tid = threadIdx.x;  // 128 threads
    __shared__ float qs[128];
    qs[tid] = qstar[b * 128 + tid];
    __syncthreads();
    float mu = bmu[tid], lv = blv[tid];
    for (int j = 0; j < 128; j++) {
        float qv = qs[j];
        mu += qv * Wmu[j * 128 + tid];
        lv += qv * Wlv[j * 128 + tid];
    }
    int idx = b * 128 + tid;
    float z = epsb[idx] * expf(0.5f * lv) + mu;
    outp[idx] = z;
    outp[32768 + idx] = mu;
    outp[65536 + idx] = lv;
}

// ---------------- host ------------------------------------------------------
extern "C" void kernel_launch(void* const* d_in, const int* in_sizes, int n_in,
                              void* d_out, int out_size, void* d_ws, size_t ws_size,
                              hipStream_t stream) {
    const float* x     = (const float*)d_in[0];
    const float* eattr = (const float*)d_in[1];
    const int*   ei    = (const int*)d_in[2];
    const int*   batch = (const int*)d_in[3];
    const float* Wq = (const float*)d_in[4],  *bq = (const float*)d_in[5];
    const float* Wk = (const float*)d_in[6],  *bk = (const float*)d_in[7];
    const float* Wv = (const float*)d_in[8],  *bv = (const float*)d_in[9];
    const float* We = (const float*)d_in[10];
    const float* Ws = (const float*)d_in[11], *bs = (const float*)d_in[12];
    const float* Wb = (const float*)d_in[13];
    const float* bng = (const float*)d_in[14], *bnb = (const float*)d_in[15];
    const float* Wih = (const float*)d_in[16], *Whh = (const float*)d_in[17];
    const float* bih = (const float*)d_in[18], *bhh = (const float*)d_in[19];
    const float* Wmu = (const float*)d_in[20], *bmu = (const float*)d_in[21];
    const float* Wlv = (const float*)d_in[22], *blv = (const float*)d_in[23];
    float* fout = (float*)d_out;

    float* ws    = (float*)d_ws;
    float* h     = ws;  ws += N_N * D_D;
    float* q     = ws;  ws += N_N * HC;
    float* kk    = ws;  ws += N_N * HC;
    float* vv    = ws;  ws += N_N * HC;
    float* xr    = ws;  ws += N_N * D_D;
    float* outm  = ws;  ws += N_N * D_D;
    float* alpha = ws;  ws += E_E * H_H;
    float* mN    = ws;  ws += N_N * H_H;
    float* den   = ws;  ws += N_N * H_H;
    float* bnst  = ws;  ws += 128;
    float* hl    = ws;  ws += B_B * D_D;
    float* cl    = ws;  ws += B_B * D_D;
    float* qstar = ws;  ws += B_B * 2 * D_D;
    float* r     = ws;  ws += B_B * D_D;
    float* eN    = ws;  ws += N_N;
    float* exN   = ws;  ws += N_N;
    float* mB    = ws;  ws += B_B;
    float* denB  = ws;  ws += B_B;
    float* epsb  = ws;  ws += 32768;

    k_eps<<<128, 256, 0, stream>>>(epsb);

    const float* hin = x;
    for (int l = 0; l < 4; l++) {
        k_init_layer<<<(N_N * D_D + 255) / 256, 256, 0, stream>>>(outm, mN, den, bnst);
        k_proj<<<N_N / 8, 256, 0, stream>>>(hin,
            Wq + l * 64 * 256, bq + l * 256,
            Wk + l * 64 * 256, bk + l * 256,
            Wv + l * 64 * 256, bv + l * 256,
            Ws + l * 64 * 64, bs + l * 64,
            q, kk, vv, xr);
        k_edge_alpha<<<(E_E + 3) / 4, 256, 0, stream>>>(q, kk, eattr, We + l * 1024, ei, alpha, mN);
        k_edge_exp<<<(E_E * H_H + 255) / 256, 256, 0, stream>>>(ei, alpha, mN, den);
        k_edge_msg<<<(E_E + 3) / 4, 256, 0, stream>>>(vv, eattr, We + l * 1024, ei, alpha, den, outm);
        k_finalize<<<(N_N + 3) / 4, 256, 0, stream>>>(outm, xr, Wb + l * 192, h);
        if (l < 3) {
            k_bn_stats<<<256, 256, 0, stream>>>(h, bnst);
            k_bn_apply<<<(N_N * D_D + 255) / 256, 256, 0, stream>>>(h, bnst, bng + l * 64, bnb + l * 64);
        }
        hin = h;
    }

    k_s2s_init<<<(B_B * 2 * D_D + 255) / 256, 256, 0, stream>>>(hl, cl, qstar);
    for (int s = 0; s < 4; s++) {
        k_lstm<<<B_B, 256, 0, stream>>>(qstar, hl, cl, Wih, Whh, bih, bhh, mB, denB, r);
        k_s2s_dot<<<(N_N + 3) / 4, 256, 0, stream>>>(h, hl, batch, eN, mB);
        k_s2s_exp<<<(N_N + 255) / 256, 256, 0, stream>>>(batch, eN, mB, exN, denB);
        k_s2s_r<<<(N_N + 3) / 4, 256, 0, stream>>>(h, batch, exN, denB, r);
        k_s2s_q<<<(B_B * 2 * D_D + 255) / 256, 256, 0, stream>>>(hl, r, qstar);
    }
    k_final<<<B_B, 128, 0, stream>>>(qstar, Wmu, bmu, Wlv, blv, epsb, fout);
}

// Round 21
// 1485.093 us; speedup vs baseline: 1.0665x; 1.0665x over previous
//
#include <hip/hip_runtime.h>
#include <hip/hip_bf16.h>
#include <hip/hip_fp16.h>
#include <math.h>
#include <stdint.h>

#define N_N 20000
#define E_E 320000
#define B_B 256
#define D_D 64
#define H_H 4
#define HC  256
#define SCALE_ 0.125f   // 1/sqrt(64)

struct h4v { __half x, y, z, w; };

__device__ __forceinline__ float sigmoidf_(float x) { return 1.0f / (1.0f + expf(-x)); }

__device__ __forceinline__ void atomicMaxF(float* addr, float val) {
    if (val >= 0.0f) atomicMax((int*)addr, __float_as_int(val));
    else             atomicMin((unsigned int*)addr, __float_as_uint(val));
}

// ---------------- Threefry2x32 (KAT-verified r5) ----------------------------
__device__ __forceinline__ void tf_round(uint32_t& x0, uint32_t& x1, int R) {
    x0 += x1; x1 = (x1 << R) | (x1 >> (32 - R)); x1 ^= x0;
}
__device__ void threefry2x32(uint32_t k0, uint32_t k1, uint32_t c0, uint32_t c1,
                             uint32_t& o0, uint32_t& o1) {
    const int rot[8] = {13, 15, 26, 6, 17, 29, 16, 24};
    uint32_t ks[3] = {k0, k1, k0 ^ k1 ^ 0x1BD11BDAu};
    uint32_t x0 = c0 + ks[0], x1 = c1 + ks[1];
#pragma unroll
    for (int g = 0; g < 5; ++g) {
        const int base = (g & 1) ? 4 : 0;
        tf_round(x0, x1, rot[base + 0]); tf_round(x0, x1, rot[base + 1]);
        tf_round(x0, x1, rot[base + 2]); tf_round(x0, x1, rot[base + 3]);
        x0 += ks[(g + 1) % 3]; x1 += ks[(g + 2) % 3] + (uint32_t)(g + 1);
    }
    o0 = x0; o1 = x1;
}

__device__ __forceinline__ float jax_n32(uint32_t bits) {
    float f = __uint_as_float((bits >> 9) | 0x3f800000u) - 1.0f;
    const float lo = -0x1.fffffep-1f;
    float u = 2.0f * f + lo;
    u = fmaxf(lo, u);
    return 1.41421356237f * erfinvf(u);
}

// eps: jax partitionable 32-bit = XOR fold of threefry output pair (r20 PASS)
__global__ void k_eps(float* __restrict__ eps) {
    int i = blockIdx.x * 256 + threadIdx.x;
    if (i >= 32768) return;
    uint32_t o0, o1;
    threefry2x32(0u, 42u, 0u, (uint32_t)i, o0, o1);
    eps[i] = jax_n32(o0 ^ o1);
}

// ---------------- init ------------------------------------------------------
__global__ void k_zero512(float* __restrict__ bnst) {
    int t = blockIdx.x * 256 + threadIdx.x;
    if (t < 512) bnst[t] = 0.0f;
}

__global__ void k_init_layer(float* __restrict__ outm, float* __restrict__ den) {
    int t = blockIdx.x * 256 + threadIdx.x;
    if (t < N_N * D_D) outm[t] = 0.0f;
    if (t < N_N * H_H) den[t] = 0.0f;
}

// ---------------- fused projection (+BN of previous layer) ------------------
// q,k,v written fp16 in transposed node layout: [n][chan(64)][head(4)]
__global__ void k_proj(const float* __restrict__ hin,
                       const float* __restrict__ Wq, const float* __restrict__ bq,
                       const float* __restrict__ Wk, const float* __restrict__ bk,
                       const float* __restrict__ Wv, const float* __restrict__ bv,
                       const float* __restrict__ Ws, const float* __restrict__ bs,
                       const float* __restrict__ bnstPrev,
                       const float* __restrict__ gam, const float* __restrict__ bet,
                       int useBN,
                       __half* __restrict__ qh, __half* __restrict__ kh,
                       __half* __restrict__ vh, float* __restrict__ xr) {
    __shared__ float hs[8][64];
    const int i0 = blockIdx.x * 8;
    const int tid = threadIdx.x;
    for (int t = tid; t < 8 * 64; t += 256) {
        float v = hin[i0 * 64 + t];
        if (useBN) {
            int d = t & 63;
            float mu = bnstPrev[d] * (1.0f / N_N);
            float var = bnstPrev[64 + d] * (1.0f / N_N) - mu * mu;
            v = gam[d] * (v - mu) * rsqrtf(var + 1e-5f) + bet[d];
        }
        hs[t >> 6][t & 63] = v;
    }
    __syncthreads();
    const int c = tid;
    const int co = (c & 63) * 4 + (c >> 6);   // transposed slot
    float acc[8];
    {
        float b = bq[c];
#pragma unroll
        for (int r = 0; r < 8; r++) acc[r] = b;
        for (int d = 0; d < 64; d++) {
            float w = Wq[d * 256 + c];
#pragma unroll
            for (int r = 0; r < 8; r++) acc[r] += hs[r][d] * w;
        }
#pragma unroll
        for (int r = 0; r < 8; r++) qh[(size_t)(i0 + r) * 256 + co] = __float2half(acc[r]);
    }
    {
        float b = bk[c];
#pragma unroll
        for (int r = 0; r < 8; r++) acc[r] = b;
        for (int d = 0; d < 64; d++) {
            float w = Wk[d * 256 + c];
#pragma unroll
            for (int r = 0; r < 8; r++) acc[r] += hs[r][d] * w;
        }
#pragma unroll
        for (int r = 0; r < 8; r++) kh[(size_t)(i0 + r) * 256 + co] = __float2half(acc[r]);
    }
    {
        float b = bv[c];
#pragma unroll
        for (int r = 0; r < 8; r++) acc[r] = b;
        for (int d = 0; d < 64; d++) {
            float w = Wv[d * 256 + c];
#pragma unroll
            for (int r = 0; r < 8; r++) acc[r] += hs[r][d] * w;
        }
#pragma unroll
        for (int r = 0; r < 8; r++) vh[(size_t)(i0 + r) * 256 + co] = __float2half(acc[r]);
    }
    if (c < 64) {
        float b = bs[c];
#pragma unroll
        for (int r = 0; r < 8; r++) acc[r] = b;
        for (int d = 0; d < 64; d++) {
            float w = Ws[d * 64 + c];
#pragma unroll
            for (int r = 0; r < 8; r++) acc[r] += hs[r][d] * w;
        }
#pragma unroll
        for (int r = 0; r < 8; r++) xr[(i0 + r) * 64 + c] = acc[r];
    }
}

// ---------------- edge pass 1: alpha -> exp + den (no max pass; bounded) ----
__global__ void k_edge_alpha(const __half* __restrict__ qh, const __half* __restrict__ kh,
                             const float* __restrict__ eattr, const float* __restrict__ We,
                             const int* __restrict__ ei,
                             float* __restrict__ alpha, float* __restrict__ den) {
    int e = blockIdx.x * 4 + (threadIdx.x >> 6);
    if (e >= E_E) return;
    int lane = threadIdx.x & 63;
    int src = ei[e], dst = ei[E_E + e];
    float4 at = *(const float4*)(eattr + (size_t)e * 4);
    h4v q4 = *(const h4v*)(qh + (size_t)dst * 256 + lane * 4);
    h4v k4 = *(const h4v*)(kh + (size_t)src * 256 + lane * 4);
    float part[4];
#pragma unroll
    for (int h = 0; h < 4; h++) {
        int c = h * 64 + lane;
        float ev = at.x * We[c] + at.y * We[256 + c] + at.z * We[512 + c] + at.w * We[768 + c];
        float qe = __half2float(h == 0 ? q4.x : (h == 1 ? q4.y : (h == 2 ? q4.z : q4.w)));
        float ke = __half2float(h == 0 ? k4.x : (h == 1 ? k4.y : (h == 2 ? k4.z : k4.w)));
        part[h] = qe * (ke + ev);
    }
#pragma unroll
    for (int off = 32; off > 0; off >>= 1) {
#pragma unroll
        for (int h = 0; h < 4; h++) part[h] += __shfl_down(part[h], off);
    }
    if (lane == 0) {
        float4 o;
        o.x = expf(part[0] * SCALE_);
        o.y = expf(part[1] * SCALE_);
        o.z = expf(part[2] * SCALE_);
        o.w = expf(part[3] * SCALE_);
        *(float4*)(alpha + (size_t)e * 4) = o;
        atomicAdd(&den[dst * 4 + 0], o.x);
        atomicAdd(&den[dst * 4 + 1], o.y);
        atomicAdd(&den[dst * 4 + 2], o.z);
        atomicAdd(&den[dst * 4 + 3], o.w);
    }
}

// ---------------- edge pass 2: weighted message + head mean -----------------
__global__ void k_edge_msg(const __half* __restrict__ vh, const float* __restrict__ eattr,
                           const float* __restrict__ We, const int* __restrict__ ei,
                           const float* __restrict__ exA, const float* __restrict__ den,
                           float* __restrict__ outm) {
    int e = blockIdx.x * 4 + (threadIdx.x >> 6);
    if (e >= E_E) return;
    int lane = threadIdx.x & 63;
    int src = ei[e], dst = ei[E_E + e];
    float4 at = *(const float4*)(eattr + (size_t)e * 4);
    float4 exv = *(const float4*)(exA + (size_t)e * 4);
    float4 dnv = *(const float4*)(den + (size_t)dst * 4);
    float aw[4] = {exv.x / (dnv.x + 1e-16f), exv.y / (dnv.y + 1e-16f),
                   exv.z / (dnv.z + 1e-16f), exv.w / (dnv.w + 1e-16f)};
    h4v v4 = *(const h4v*)(vh + (size_t)src * 256 + lane * 4);
    float acc = 0.0f;
#pragma unroll
    for (int h = 0; h < 4; h++) {
        int c = h * 64 + lane;
        float ev = at.x * We[c] + at.y * We[256 + c] + at.z * We[512 + c] + at.w * We[768 + c];
        float ve = __half2float(h == 0 ? v4.x : (h == 1 ? v4.y : (h == 2 ? v4.z : v4.w)));
        acc += aw[h] * (ve + ev);
    }
    atomicAdd(&outm[dst * 64 + lane], acc * 0.25f);
}

// ---------------- beta gate + relu ------------------------------------------
__global__ void k_finalize(const float* __restrict__ outm, const float* __restrict__ xr,
                           const float* __restrict__ Wb, float* __restrict__ h) {
    int i = blockIdx.x * 4 + (threadIdx.x >> 6);
    if (i >= N_N) return;
    int lane = threadIdx.x & 63;
    float o = outm[i * 64 + lane], x = xr[i * 64 + lane];
    float p = o * Wb[lane] + x * Wb[64 + lane] + (o - x) * Wb[128 + lane];
#pragma unroll
    for (int off = 32; off > 0; off >>= 1) p += __shfl_down(p, off);
    float s = __shfl(p, 0);
    float beta = sigmoidf_(s);
    float val = beta * x + (1.0f - beta) * o;
    h[i * 64 + lane] = fmaxf(val, 0.0f);
}

// ---------------- batchnorm stats (apply fused into next k_proj) ------------
__global__ void k_bn_stats(const float* __restrict__ h, float* __restrict__ bnst) {
    int c = threadIdx.x & 63, g = threadIdx.x >> 6;
    float s = 0.0f, s2 = 0.0f;
    for (int i = blockIdx.x * 4 + g; i < N_N; i += gridDim.x * 4) {
        float v = h[i * 64 + c];
        s += v; s2 += v * v;
    }
    atomicAdd(&bnst[c], s);
    atomicAdd(&bnst[64 + c], s2);
}

// ---------------- set2set ---------------------------------------------------
__global__ void k_s2s_init(float* __restrict__ hl, float* __restrict__ cl,
                           float* __restrict__ qstar) {
    int t = blockIdx.x * 256 + threadIdx.x;
    if (t < B_B * D_D) { hl[t] = 0.0f; cl[t] = 0.0f; }
    if (t < B_B * 2 * D_D) qstar[t] = 0.0f;
}

__global__ void k_lstm(const float* __restrict__ qstar, float* __restrict__ hl,
                       float* __restrict__ cl,
                       const float* __restrict__ Wih, const float* __restrict__ Whh,
                       const float* __restrict__ bih, const float* __restrict__ bhh,
                       float* __restrict__ mB, float* __restrict__ denB, float* __restrict__ r) {
    int b = blockIdx.x, tid = threadIdx.x;
    __shared__ float qs[128], hs[64], gates[256];
    if (tid < 128) qs[tid] = qstar[b * 128 + tid];
    if (tid < 64) hs[tid] = hl[b * 64 + tid];
    __syncthreads();
    float acc = bih[tid] + bhh[tid];
    for (int j = 0; j < 128; j++) acc += qs[j] * Wih[tid * 128 + j];
    for (int j = 0; j < 64; j++) acc += hs[j] * Whh[tid * 64 + j];
    gates[tid] = acc;
    __syncthreads();
    if (tid < 64) {
        float ig = sigmoidf_(gates[tid]);
        float fg = sigmoidf_(gates[64 + tid]);
        float gg = tanhf(gates[128 + tid]);
        float og = sigmoidf_(gates[192 + tid]);
        float c = fg * cl[b * 64 + tid] + ig * gg;
        float hh = og * tanhf(c);
        cl[b * 64 + tid] = c;
        hl[b * 64 + tid] = hh;
        r[b * 64 + tid] = 0.0f;
    }
    if (tid == 0) { mB[b] = -INFINITY; denB[b] = 0.0f; }
}

__global__ void k_s2s_dot(const float* __restrict__ h, const float* __restrict__ hl,
                          const int* __restrict__ batch, float* __restrict__ eN,
                          float* __restrict__ mB) {
    int i = blockIdx.x * 4 + (threadIdx.x >> 6);
    if (i >= N_N) return;
    int lane = threadIdx.x & 63;
    int b = batch[i];
    float p = h[i * 64 + lane] * hl[b * 64 + lane];
#pragma unroll
    for (int off = 32; off > 0; off >>= 1) p += __shfl_down(p, off);
    if (lane == 0) { eN[i] = p; atomicMaxF(&mB[b], p); }
}

__global__ void k_s2s_exp(const int* __restrict__ batch, const float* __restrict__ eN,
                          const float* __restrict__ mB, float* __restrict__ exN,
                          float* __restrict__ denB) {
    int i = blockIdx.x * 256 + threadIdx.x;
    if (i >= N_N) return;
    int b = batch[i];
    float ex = expf(eN[i] - mB[b]);
    exN[i] = ex;
    atomicAdd(&denB[b], ex);
}

__global__ void k_s2s_r(const float* __restrict__ h, const int* __restrict__ batch,
                        const float* __restrict__ exN, const float* __restrict__ denB,
                        float* __restrict__ r) {
    int i = blockIdx.x * 4 + (threadIdx.x >> 6);
    if (i >= N_N) return;
    int lane = threadIdx.x & 63;
    int b = batch[i];
    float a = exN[i] / (denB[b] + 1e-16f);
    atomicAdd(&r[b * 64 + lane], a * h[i * 64 + lane]);
}

__global__ void k_s2s_q(const float* __restrict__ hl, const float* __restrict__ r,
                        float* __restrict__ qstar) {
    int t = blockIdx.x * 256 + threadIdx.x;
    if (t >= B_B * 2 * D_D) return;
    int b = t >> 7, c = t & 127;
    qstar[t] = (c < 64) ? hl[b * 64 + c] : r[b * 64 + (c - 64)];
}

// ---------------- heads + reparameterization --------------------------------
__global__ void k_final(const float* __restrict__ qstar,
                        const float* __restrict__ Wmu, const float* __restrict__ bmu,
                        const float* __restrict__ Wlv, const float* __restrict__ blv,
                        const float* __restrict__ epsb,
                        float* __restrict__ outp) {
    int b = blockIdx.x, tid = threadIdx.x;  // 128 threads
    __shared__ float qs[128];
    qs[tid] = qstar[b * 128 + tid];
    __syncthreads();
    float mu = bmu[tid], lv = blv[tid];
    for (int j = 0; j < 128; j++) {
        float qv = qs[j];
        mu += qv * Wmu[j * 128 + tid];
        lv += qv * Wlv[j * 128 + tid];
    }
    int idx = b * 128 + tid;
    float z = epsb[idx] * expf(0.5f * lv) + mu;
    outp[idx] = z;
    outp[32768 + idx] = mu;
    outp[65536 + idx] = lv;
}

// ---------------- host ------------------------------------------------------
extern "C" void kernel_launch(void* const* d_in, const int* in_sizes, int n_in,
                              void* d_out, int out_size, void* d_ws, size_t ws_size,
                              hipStream_t stream) {
    const float* x     = (const float*)d_in[0];
    const float* eattr = (const float*)d_in[1];
    const int*   ei    = (const int*)d_in[2];
    const int*   batch = (const int*)d_in[3];
    const float* Wq = (const float*)d_in[4],  *bq = (const float*)d_in[5];
    const float* Wk = (const float*)d_in[6],  *bk = (const float*)d_in[7];
    const float* Wv = (const float*)d_in[8],  *bv = (const float*)d_in[9];
    const float* We = (const float*)d_in[10];
    const float* Ws = (const float*)d_in[11], *bs = (const float*)d_in[12];
    const float* Wb = (const float*)d_in[13];
    const float* bng = (const float*)d_in[14], *bnb = (const float*)d_in[15];
    const float* Wih = (const float*)d_in[16], *Whh = (const float*)d_in[17];
    const float* bih = (const float*)d_in[18], *bhh = (const float*)d_in[19];
    const float* Wmu = (const float*)d_in[20], *bmu = (const float*)d_in[21];
    const float* Wlv = (const float*)d_in[22], *blv = (const float*)d_in[23];
    float* fout = (float*)d_out;

    float* ws    = (float*)d_ws;
    float* h     = ws;  ws += N_N * D_D;
    __half* qh   = (__half*)ws; ws += N_N * 128;   // N*256 halves
    __half* kh   = (__half*)ws; ws += N_N * 128;
    __half* vh   = (__half*)ws; ws += N_N * 128;
    float* xr    = ws;  ws += N_N * D_D;
    float* outm  = ws;  ws += N_N * D_D;
    float* alpha = ws;  ws += E_E * H_H;
    float* den   = ws;  ws += N_N * H_H;
    float* bnst  = ws;  ws += 512;                 // 4 layers x 128
    float* hl    = ws;  ws += B_B * D_D;
    float* cl    = ws;  ws += B_B * D_D;
    float* qstar = ws;  ws += B_B * 2 * D_D;
    float* r     = ws;  ws += B_B * D_D;
    float* eN    = ws;  ws += N_N;
    float* exN   = ws;  ws += N_N;
    float* mB    = ws;  ws += B_B;
    float* denB  = ws;  ws += B_B;
    float* epsb  = ws;  ws += 32768;

    k_eps<<<128, 256, 0, stream>>>(epsb);
    k_zero512<<<2, 256, 0, stream>>>(bnst);

    const float* hin = x;
    for (int l = 0; l < 4; l++) {
        k_init_layer<<<(N_N * D_D + 255) / 256, 256, 0, stream>>>(outm, den);
        k_proj<<<N_N / 8, 256, 0, stream>>>(hin,
            Wq + l * 64 * 256, bq + l * 256,
            Wk + l * 64 * 256, bk + l * 256,
            Wv + l * 64 * 256, bv + l * 256,
            Ws + l * 64 * 64, bs + l * 64,
            bnst + (l > 0 ? (l - 1) * 128 : 0),
            bng + (l > 0 ? (l - 1) * 64 : 0), bnb + (l > 0 ? (l - 1) * 64 : 0),
            (l > 0) ? 1 : 0,
            qh, kh, vh, xr);
        k_edge_alpha<<<(E_E + 3) / 4, 256, 0, stream>>>(qh, kh, eattr, We + l * 1024, ei, alpha, den);
        k_edge_msg<<<(E_E + 3) / 4, 256, 0, stream>>>(vh, eattr, We + l * 1024, ei, alpha, den, outm);
        k_finalize<<<(N_N + 3) / 4, 256, 0, stream>>>(outm, xr, Wb + l * 192, h);
        if (l < 3) {
            k_bn_stats<<<256, 256, 0, stream>>>(h, bnst + l * 128);
        }
        hin = h;
    }

    k_s2s_init<<<(B_B * 2 * D_D + 255) / 256, 256, 0, stream>>>(hl, cl, qstar);
    for (int s = 0; s < 4; s++) {
        k_lstm<<<B_B, 256, 0, stream>>>(qstar, hl, cl, Wih, Whh, bih, bhh, mB, denB, r);
        k_s2s_dot<<<(N_N + 3) / 4, 256, 0, stream>>>(h, hl, batch, eN, mB);
        k_s2s_exp<<<(N_N + 255) / 256, 256, 0, stream>>>(batch, eN, mB, exN, denB);
        k_s2s_r<<<(N_N + 3) / 4, 256, 0, stream>>>(h, batch, exN, denB, r);
        k_s2s_q<<<(B_B * 2 * D_D + 255) / 256, 256, 0, stream>>>(hl, r, qstar);
    }
    k_final<<<B_B, 128, 0, stream>>>(qstar, Wmu, bmu, Wlv, blv, epsb, fout);
}